// Round 1
// baseline (3505.572 us; speedup 1.0000x reference)
//
#include <hip/hip_runtime.h>
#include <hip/hip_bf16.h>
#include <cstdint>

#define Bb 64
#define Cc 64
#define Tt 2048
#define Hh 128
// 4*H = 512 gate rows per direction

__device__ __forceinline__ float fast_sigmoid(float x) {
    return 1.0f / (1.0f + __expf(-x));
}
__device__ __forceinline__ float fast_tanh(float x) {
    // (1 - e^-2x)/(1 + e^-2x), saturates correctly for large |x|
    return 1.0f - 2.0f / (__expf(2.0f * x) + 1.0f);
}

// ---------------- Kernel 1: fused bidirectional LSTM ----------------
// grid: 128 blocks = (dir * 64 + b), block: 512 threads (thread = gate row g)
// Weights held in registers (192 fp32/thread). x staged in LDS 64-step tiles.
// Writes lstm_out y[b][t][dir*128 + j] as bf16.
__global__ __launch_bounds__(512) void lstm_kernel(
    const float* __restrict__ x,
    const float* __restrict__ Wih_f, const float* __restrict__ Whh_f,
    const float* __restrict__ bih_f, const float* __restrict__ bhh_f,
    const float* __restrict__ Wih_b, const float* __restrict__ Whh_b,
    const float* __restrict__ bih_b, const float* __restrict__ bhh_b,
    __hip_bfloat16* __restrict__ y)
{
    const int blk = blockIdx.x;
    const int dir = blk >> 6;      // 0 = fwd, 1 = bwd
    const int b   = blk & 63;
    const int g   = threadIdx.x;   // gate row 0..511

    const float* Wih = dir ? Wih_b : Wih_f;
    const float* Whh = dir ? Whh_b : Whh_f;
    const float* bih = dir ? bih_b : bih_f;
    const float* bhh = dir ? bhh_b : bhh_f;

    // per-thread weight rows in registers (compile-time indices only -> VGPRs)
    float wih[64];
    float whh[128];
    #pragma unroll
    for (int c0 = 0; c0 < 16; ++c0) {
        float4 v = *(const float4*)(Wih + g * 64 + c0 * 4);
        wih[c0*4+0] = v.x; wih[c0*4+1] = v.y; wih[c0*4+2] = v.z; wih[c0*4+3] = v.w;
    }
    #pragma unroll
    for (int k0 = 0; k0 < 32; ++k0) {
        float4 v = *(const float4*)(Whh + g * 128 + k0 * 4);
        whh[k0*4+0] = v.x; whh[k0*4+1] = v.y; whh[k0*4+2] = v.z; whh[k0*4+3] = v.w;
    }
    const float bias = bih[g] + bhh[g];

    __shared__ float xs[64 * 68];   // [tt][c], padded row stride 68 floats
    __shared__ float hs[128];
    __shared__ float zs[512];

    if (g < 128) hs[g] = 0.0f;
    float cst = 0.0f;
    __syncthreads();

    for (int s0 = 0; s0 < Tt; s0 += 64) {
        const int tile_lo = dir ? (Tt - 64 - s0) : s0;
        // stage x[b][:][tile_lo .. tile_lo+63] (coalesced along t)
        #pragma unroll
        for (int r = 0; r < 2; ++r) {
            int idx = r * 512 + g;            // 0..1023
            int c = idx >> 4, q = idx & 15;   // q*4 = tt base
            float4 v = *(const float4*)(x + ((size_t)b * Cc + c) * Tt + tile_lo + q * 4);
            xs[(q*4+0)*68 + c] = v.x;
            xs[(q*4+1)*68 + c] = v.y;
            xs[(q*4+2)*68 + c] = v.z;
            xs[(q*4+3)*68 + c] = v.w;
        }
        __syncthreads();
        for (int ss = 0; ss < 64; ++ss) {
            const int s  = s0 + ss;
            const int t  = dir ? (Tt - 1 - s) : s;
            const int tt = dir ? (63 - ss) : ss;

            float z = bias;
            const float* xrow = &xs[tt * 68];
            #pragma unroll
            for (int c0 = 0; c0 < 16; ++c0) {   // input projection (broadcast LDS reads)
                float4 v = *(const float4*)(xrow + c0 * 4);
                z += wih[c0*4+0]*v.x + wih[c0*4+1]*v.y + wih[c0*4+2]*v.z + wih[c0*4+3]*v.w;
            }
            #pragma unroll
            for (int k0 = 0; k0 < 32; ++k0) {   // recurrent part
                float4 v = *(const float4*)(&hs[k0*4]);
                z += whh[k0*4+0]*v.x + whh[k0*4+1]*v.y + whh[k0*4+2]*v.z + whh[k0*4+3]*v.w;
            }
            zs[g] = z;
            __syncthreads();
            if (g < 128) {
                float zi = zs[g], zf = zs[128+g], zg = zs[256+g], zo = zs[384+g];
                cst = fast_sigmoid(zf) * cst + fast_sigmoid(zi) * fast_tanh(zg);
                float h = fast_sigmoid(zo) * fast_tanh(cst);
                hs[g] = h;
                y[((size_t)b * Tt + t) * 256 + dir * 128 + g] = __float2bfloat16(h);
            }
            __syncthreads();
        }
    }
}

// ---------------- Kernel 2: attention scores ----------------
// scores[b][t] = Wu . tanh(Wa @ y[b][t] + ba) + bu
// grid: (T/32, B), block 256 (thread = u-row g); 32 t's per block.
__global__ __launch_bounds__(256) void attn_scores_kernel(
    const __hip_bfloat16* __restrict__ y,
    const float* __restrict__ Wa, const float* __restrict__ ba,
    const float* __restrict__ Wu, const float* __restrict__ bu,
    float* __restrict__ scores)
{
    const int b  = blockIdx.y;
    const int t0 = blockIdx.x * 32;
    const int g  = threadIdx.x;

    __shared__ float ylds[32 * 256];
    __shared__ float red[32][4];

    const unsigned short* yb = (const unsigned short*)y + ((size_t)b * Tt + t0) * 256;
    #pragma unroll
    for (int r = 0; r < 4; ++r) {
        int base = (r * 256 + g) * 8;
        uint4 v = *(const uint4*)(yb + base);   // 8 bf16
        ylds[base+0] = __uint_as_float(v.x << 16);
        ylds[base+1] = __uint_as_float(v.x & 0xffff0000u);
        ylds[base+2] = __uint_as_float(v.y << 16);
        ylds[base+3] = __uint_as_float(v.y & 0xffff0000u);
        ylds[base+4] = __uint_as_float(v.z << 16);
        ylds[base+5] = __uint_as_float(v.z & 0xffff0000u);
        ylds[base+6] = __uint_as_float(v.w << 16);
        ylds[base+7] = __uint_as_float(v.w & 0xffff0000u);
    }
    __syncthreads();

    float uacc[32];
    #pragma unroll
    for (int t = 0; t < 32; ++t) uacc[t] = 0.0f;

    const float4* wa4 = (const float4*)(Wa + (size_t)g * 256);
    for (int k0 = 0; k0 < 64; ++k0) {
        float4 w = wa4[k0];
        #pragma unroll
        for (int t = 0; t < 32; ++t) {
            float4 v = *(const float4*)(&ylds[t * 256 + k0 * 4]);
            uacc[t] += w.x*v.x + w.y*v.y + w.z*v.z + w.w*v.w;
        }
    }

    const float bag = ba[g];
    const float wug = Wu[g];
    const int lane = g & 63, wid = g >> 6;
    #pragma unroll
    for (int t = 0; t < 32; ++t) {
        float val = wug * fast_tanh(uacc[t] + bag);
        #pragma unroll
        for (int off = 32; off >= 1; off >>= 1)
            val += __shfl_down(val, off, 64);
        if (lane == 0) red[t][wid] = val;
    }
    __syncthreads();
    if (g < 32) {
        float s = red[g][0] + red[g][1] + red[g][2] + red[g][3] + bu[0];
        scores[(size_t)b * Tt + t0 + g] = s;
    }
}

// ---------------- Kernel 3: softmax over T + weighted sum ----------------
// grid: B blocks, block 256 (thread = output dim j)
__global__ __launch_bounds__(256) void attn_out_kernel(
    const __hip_bfloat16* __restrict__ y,
    const float* __restrict__ scores,
    float* __restrict__ out)
{
    const int b = blockIdx.x;
    const int tid = threadIdx.x;
    const int lane = tid & 63, wid = tid >> 6;
    __shared__ float wls[2048];
    __shared__ float red[4];

    // max
    float m = -1e30f;
    for (int t = tid; t < Tt; t += 256) m = fmaxf(m, scores[(size_t)b*Tt + t]);
    #pragma unroll
    for (int off = 32; off >= 1; off >>= 1) m = fmaxf(m, __shfl_xor(m, off, 64));
    if (lane == 0) red[wid] = m;
    __syncthreads();
    m = fmaxf(fmaxf(red[0], red[1]), fmaxf(red[2], red[3]));
    __syncthreads();

    // exp + sum
    float sum = 0.0f;
    for (int t = tid; t < Tt; t += 256) {
        float e = __expf(scores[(size_t)b*Tt + t] - m);
        wls[t] = e;
        sum += e;
    }
    #pragma unroll
    for (int off = 32; off >= 1; off >>= 1) sum += __shfl_xor(sum, off, 64);
    if (lane == 0) red[wid] = sum;
    __syncthreads();
    const float inv = 1.0f / (red[0] + red[1] + red[2] + red[3]);

    // weighted sum over t (coalesced across lanes)
    const unsigned short* yb = (const unsigned short*)y + (size_t)b * Tt * 256 + tid;
    float acc = 0.0f;
    for (int t = 0; t < Tt; ++t) {
        acc += wls[t] * __uint_as_float(((unsigned)yb[(size_t)t * 256]) << 16);
    }
    out[b * 256 + tid] = acc * inv;
}

extern "C" void kernel_launch(void* const* d_in, const int* in_sizes, int n_in,
                              void* d_out, int out_size, void* d_ws, size_t ws_size,
                              hipStream_t stream) {
    const float* x     = (const float*)d_in[0];
    const float* Wih_f = (const float*)d_in[1];
    const float* Whh_f = (const float*)d_in[2];
    const float* bih_f = (const float*)d_in[3];
    const float* bhh_f = (const float*)d_in[4];
    const float* Wih_b = (const float*)d_in[5];
    const float* Whh_b = (const float*)d_in[6];
    const float* bih_b = (const float*)d_in[7];
    const float* bhh_b = (const float*)d_in[8];
    const float* Wa    = (const float*)d_in[9];
    const float* ba    = (const float*)d_in[10];
    const float* Wu    = (const float*)d_in[11];
    const float* bu    = (const float*)d_in[12];
    float* out = (float*)d_out;

    // workspace layout: y (B*T*256 bf16 = 64 MiB) | scores (B*T fp32 = 0.5 MiB)
    __hip_bfloat16* y = (__hip_bfloat16*)d_ws;
    float* scores = (float*)((char*)d_ws + (size_t)Bb * Tt * 256 * sizeof(__hip_bfloat16));

    hipLaunchKernelGGL(lstm_kernel, dim3(128), dim3(512), 0, stream,
                       x, Wih_f, Whh_f, bih_f, bhh_f, Wih_b, Whh_b, bih_b, bhh_b, y);
    hipLaunchKernelGGL(attn_scores_kernel, dim3(Tt / 32, Bb), dim3(256), 0, stream,
                       y, Wa, ba, Wu, bu, scores);
    hipLaunchKernelGGL(attn_out_kernel, dim3(Bb), dim3(256), 0, stream, y, scores, out);
}